// Round 5
// baseline (174.139 us; speedup 1.0000x reference)
//
#include <hip/hip_runtime.h>
#include <hip/hip_bf16.h>

#define BATCH 8192
#define IN_F  2048
#define OUT_F 2048
#define QB    7.0f
#define EPSV  1e-5f
#define ASCALE 18.0f            // xq_i8 = round(xq * 18) in [-126,126]

typedef char  i8x4 __attribute__((ext_vector_type(4)));
typedef int   i32x4 __attribute__((ext_vector_type(4)));

#define AS1(p) ((__attribute__((address_space(1))) void*)(p))
#define AS3(p) ((__attribute__((address_space(3))) void*)(p))

__device__ __forceinline__ float waveReduceSum(float v) {
#pragma unroll
  for (int off = 32; off > 0; off >>= 1) v += __shfl_xor(v, off, 64);
  return v;
}
__device__ __forceinline__ float waveReduceMax(float v) {
#pragma unroll
  for (int off = 32; off > 0; off >>= 1) v = fmaxf(v, __shfl_xor(v, off, 64));
  return v;
}

// ---------------- Fused preprocessing ----------------
// blocks [0, OUT_F): weight row -> wbin i8 {-1,0,1} (exact), beta
// blocks [OUT_F, OUT_F+BATCH): LN+clip row -> xq i8 = round(clip*18), gama
__global__ __launch_bounds__(256) void prep_kernel(const float* __restrict__ x,
                                                   const float* __restrict__ w,
                                                   char* __restrict__ xq,
                                                   char* __restrict__ wb,
                                                   float* __restrict__ gamaOut,
                                                   float* __restrict__ betaOut) {
  __shared__ float red[8];
  const int t = threadIdx.x;
  const int wave = t >> 6, lane = t & 63;

  if (blockIdx.x < OUT_F) {
    const int row = blockIdx.x;
    const float* wr = w + (size_t)row * IN_F;
    float4 v0 = ((const float4*)wr)[t];
    float4 v1 = ((const float4*)wr)[t + 256];
    float s  = v0.x + v0.y + v0.z + v0.w + v1.x + v1.y + v1.z + v1.w;
    float sa = fabsf(v0.x) + fabsf(v0.y) + fabsf(v0.z) + fabsf(v0.w)
             + fabsf(v1.x) + fabsf(v1.y) + fabsf(v1.z) + fabsf(v1.w);
    float wsum = waveReduceSum(s);
    float wsa  = waveReduceSum(sa);
    if (lane == 0) { red[wave] = wsum; red[4 + wave] = wsa; }
    __syncthreads();
    const float mu   = (red[0] + red[1] + red[2] + red[3]) * (1.0f / IN_F);
    const float beta = (red[4] + red[5] + red[6] + red[7]) * (1.0f / IN_F);
    if (t == 0) betaOut[row] = beta;

    char* wbr = wb + (size_t)row * IN_F;
    auto sgn = [&](float xv) -> char {
      float d = xv - mu;
      return (char)((d > 0.0f) ? 1 : (d < 0.0f ? -1 : 0));
    };
    i8x4 q0 = { sgn(v0.x), sgn(v0.y), sgn(v0.z), sgn(v0.w) };
    i8x4 q1 = { sgn(v1.x), sgn(v1.y), sgn(v1.z), sgn(v1.w) };
    ((i8x4*)wbr)[t]       = q0;
    ((i8x4*)wbr)[t + 256] = q1;
  } else {
    const int row = blockIdx.x - OUT_F;
    const float* xr = x + (size_t)row * IN_F;
    float4 v0 = ((const float4*)xr)[t];
    float4 v1 = ((const float4*)xr)[t + 256];
    float s  = v0.x + v0.y + v0.z + v0.w + v1.x + v1.y + v1.z + v1.w;
    float s2 = v0.x*v0.x + v0.y*v0.y + v0.z*v0.z + v0.w*v0.w
             + v1.x*v1.x + v1.y*v1.y + v1.z*v1.z + v1.w*v1.w;
    float wsum  = waveReduceSum(s);
    float wsum2 = waveReduceSum(s2);
    if (lane == 0) { red[wave] = wsum; red[4 + wave] = wsum2; }
    __syncthreads();
    const float mu  = (red[0] + red[1] + red[2] + red[3]) * (1.0f / IN_F);
    const float ex2 = (red[4] + red[5] + red[6] + red[7]) * (1.0f / IN_F);
    const float rstd = rsqrtf(fmaxf(ex2 - mu * mu, 0.0f) + EPSV);

    float n[8];
    n[0] = (v0.x - mu) * rstd; n[1] = (v0.y - mu) * rstd;
    n[2] = (v0.z - mu) * rstd; n[3] = (v0.w - mu) * rstd;
    n[4] = (v1.x - mu) * rstd; n[5] = (v1.y - mu) * rstd;
    n[6] = (v1.z - mu) * rstd; n[7] = (v1.w - mu) * rstd;
    float amax = 0.0f;
#pragma unroll
    for (int j = 0; j < 8; ++j) amax = fmaxf(amax, fabsf(n[j]));

    __syncthreads();
    float wmax = waveReduceMax(amax);
    if (lane == 0) red[wave] = wmax;
    __syncthreads();
    const float g = fmaxf(fmaxf(fmaxf(red[0], red[1]), fmaxf(red[2], red[3])), EPSV);
    if (t == 0) gamaOut[row] = g;

    const float qs = (QB * ASCALE) / g;           // 126/g
    const float lo = (-QB + EPSV) * ASCALE, hi = (QB - EPSV) * ASCALE;
    auto qz = [&](float v) -> char {
      return (char)__float2int_rn(fminf(fmaxf(v * qs, lo), hi));
    };
    char* xqr = xq + (size_t)row * IN_F;
    i8x4 q0 = { qz(n[0]), qz(n[1]), qz(n[2]), qz(n[3]) };
    i8x4 q1 = { qz(n[4]), qz(n[5]), qz(n[6]), qz(n[7]) };
    ((i8x4*)xqr)[t]       = q0;
    ((i8x4*)xqr)[t + 256] = q1;
  }
}

// ---------------- GEMM: i8, 128x128 tile, BK=64, double-buffered LDS --------
// out[b,o] = i32dot(xq_i8[b,:], wbin[o,:]) * beta[o]*gama[b]/(7*18) + bias[o]
// 32 K-iters; ONE barrier per iter. Loads for iter k+1 are issued right after
// the barrier into buf^1 while 16 MFMAs (~320 cyc) compute from buf -> the
// next barrier's vmcnt(0) drains loads that had a full compute phase in
// flight (L2 latency ~200 cyc hidden).
// LDS rows = 64 B = 4 chunks of 16 B. Swizzle: slot s of row r holds global
// chunk (s - (r>>1)) & 3 -> read of chunk kh from row fr hits slot
// (kh + (fr>>1)) & 3. Bank audit per quarter-wave: start quads
// {0,4,..,28} each 2x -> conflict-free (2-way is free, m136).
__global__ __launch_bounds__(256) void gemm_kernel(const char* __restrict__ A,
                                                   const char* __restrict__ B,
                                                   const float* __restrict__ beta,
                                                   const float* __restrict__ gama,
                                                   const float* __restrict__ bias,
                                                   float* __restrict__ out) {
  __shared__ __align__(16) char As[2][128 * 64];
  __shared__ __align__(16) char Bs[2][128 * 64];

  const int t = threadIdx.x;
  const int wave = t >> 6, lane = t & 63;
  const int mBase = blockIdx.y * 128;
  const int nBase = blockIdx.x * 128;
  const int wm = (wave >> 1) * 64;
  const int wn = (wave & 1) * 64;

  i32x4 acc[4][4];
#pragma unroll
  for (int i = 0; i < 4; ++i)
#pragma unroll
    for (int j = 0; j < 4; ++j) {
      i32x4 z = {0, 0, 0, 0};
      acc[i][j] = z;
    }

  // ---- staging: wave w covers rows [w*32, w*32+32), 2 instrs of 16 rows
  // each (A and B). lane l -> row lr = l>>2, slot ls = l&3,
  // global chunk gch = (ls - (lr>>1)) & 3.
  const int lr = lane >> 2;
  const int ls = lane & 3;
  const int gch = (ls - (lr >> 1)) & 3;
  const char* aG[2];
  const char* bG[2];
  int ldsOff[2];
#pragma unroll
  for (int j = 0; j < 2; ++j) {
    const int rowInTile = wave * 32 + j * 16 + lr;
    aG[j] = A + (size_t)(mBase + rowInTile) * IN_F + gch * 16;
    bG[j] = B + (size_t)(nBase + rowInTile) * IN_F + gch * 16;
    ldsOff[j] = (wave * 32 + j * 16) * 64;   // wave-uniform; HW adds lane*16B
  }

  // ---- fragment: A[m = lane&15][k = (lane>>4)*16 + 0..15]; chunk kh = lane>>4
  // slot = (kh + (fr>>1)) & 3
  const int fr = lane & 15;
  const int kq = lane >> 4;
  const int koff = ((kq + (fr >> 1)) & 3) * 16;
  const int aFoff = (wm + fr) * 64 + koff;
  const int bFoff = (wn + fr) * 64 + koff;

  // prologue: stage tile 0 into buffer 0
#pragma unroll
  for (int j = 0; j < 2; ++j) {
    __builtin_amdgcn_global_load_lds(AS1(aG[j]), AS3(&As[0][0] + ldsOff[j]), 16, 0, 0);
    __builtin_amdgcn_global_load_lds(AS1(bG[j]), AS3(&Bs[0][0] + ldsOff[j]), 16, 0, 0);
  }

  int cur = 0;
  for (int it = 0; it < IN_F / 64; ++it) {
    __syncthreads();   // buf[cur] loads drained; buf[cur^1] free of readers
    if (it + 1 < IN_F / 64) {
      const int k0 = (it + 1) * 64;
      char* aDst = &As[cur ^ 1][0];
      char* bDst = &Bs[cur ^ 1][0];
#pragma unroll
      for (int j = 0; j < 2; ++j) {
        __builtin_amdgcn_global_load_lds(AS1(aG[j] + k0), AS3(aDst + ldsOff[j]), 16, 0, 0);
        __builtin_amdgcn_global_load_lds(AS1(bG[j] + k0), AS3(bDst + ldsOff[j]), 16, 0, 0);
      }
    }

    const char* aF = &As[cur][0] + aFoff;
    const char* bF = &Bs[cur][0] + bFoff;
    i32x4 af[4], bf[4];
#pragma unroll
    for (int mi = 0; mi < 4; ++mi) af[mi] = *(const i32x4*)(aF + mi * 16 * 64);
#pragma unroll
    for (int ni = 0; ni < 4; ++ni) bf[ni] = *(const i32x4*)(bF + ni * 16 * 64);
#pragma unroll
    for (int mi = 0; mi < 4; ++mi)
#pragma unroll
      for (int ni = 0; ni < 4; ++ni)
        acc[mi][ni] = __builtin_amdgcn_mfma_i32_16x16x64_i8(af[mi], bf[ni], acc[mi][ni], 0, 0, 0);

    cur ^= 1;
  }

  // ---- epilogue: C/D layout col = lane&15, row = (lane>>4)*4 + reg
  const float qinv = 1.0f / (QB * ASCALE);
  const int orow0 = mBase + wm + (kq << 2);
  const int ocol0 = nBase + wn + fr;
#pragma unroll
  for (int mi = 0; mi < 4; ++mi) {
    const int rbase = orow0 + mi * 16;
    const float g0 = gama[rbase + 0] * qinv;
    const float g1 = gama[rbase + 1] * qinv;
    const float g2 = gama[rbase + 2] * qinv;
    const float g3 = gama[rbase + 3] * qinv;
#pragma unroll
    for (int ni = 0; ni < 4; ++ni) {
      const int c = ocol0 + ni * 16;
      const float bsc = beta[c];
      const float bv  = bias[c];
      float* op = out + (size_t)rbase * OUT_F + c;
      op[0 * OUT_F] = (float)acc[mi][ni][0] * (bsc * g0) + bv;
      op[1 * OUT_F] = (float)acc[mi][ni][1] * (bsc * g1) + bv;
      op[2 * OUT_F] = (float)acc[mi][ni][2] * (bsc * g2) + bv;
      op[3 * OUT_F] = (float)acc[mi][ni][3] * (bsc * g3) + bv;
    }
  }
}

extern "C" void kernel_launch(void* const* d_in, const int* in_sizes, int n_in,
                              void* d_out, int out_size, void* d_ws, size_t ws_size,
                              hipStream_t stream) {
  const float* x      = (const float*)d_in[0];
  const float* weight = (const float*)d_in[1];
  const float* bias   = (const float*)d_in[2];
  float* out = (float*)d_out;

  char* ws = (char*)d_ws;
  char* wbin = ws;                                                  // 4 MB
  char* xq   = ws + (size_t)OUT_F * IN_F;                           // 16 MB
  float* betaW = (float*)(ws + (size_t)OUT_F * IN_F + (size_t)BATCH * IN_F);
  float* gamaX = betaW + OUT_F;

  prep_kernel<<<OUT_F + BATCH, 256, 0, stream>>>(x, weight, xq, wbin, gamaX, betaW);
  gemm_kernel<<<dim3(OUT_F / 128, BATCH / 128), 256, 0, stream>>>(xq, wbin, betaW, gamaX, bias, out);
}